// Round 9
// baseline (390.726 us; speedup 1.0000x reference)
//
#include <hip/hip_runtime.h>
#include <hip/hip_bf16.h>
#include <math.h>

#define BATCH 4
#define SEQ   2048
#define DM    512
#define NH    8
#define DK    64
#define FF    2048
#define BT    (BATCH * SEQ)   // 8192

// q pre-scale: 0.125 * log2(e)  -> softmax uses exp2 directly
#define SCALE_Q 0.18033688011112042f

typedef short bf16x8 __attribute__((ext_vector_type(8)));
typedef float f32x4  __attribute__((ext_vector_type(4)));

static __device__ inline short f2bf(float f) {
  union { float f; unsigned u; } v; v.f = f;
  unsigned r = (v.u + 0x7fffu + ((v.u >> 16) & 1u)) >> 16;
  return (short)r;
}

// async 16B global->LDS (gfx950). LDS dest = wave-uniform base + lane*16.
static __device__ __forceinline__ void gload16(const short* g, short* l) {
  __builtin_amdgcn_global_load_lds(
      (const __attribute__((address_space(1))) void*)g,
      (__attribute__((address_space(3))) void*)l, 16, 0, 0);
}

// ---------------------------------------------------------------------------
// LayerNorm: one block per row of 512, fp32 in -> bf16 out
// ---------------------------------------------------------------------------
__global__ __launch_bounds__(256) void ln_kernel(
    const float* __restrict__ x, const float* __restrict__ gamma,
    const float* __restrict__ beta, short* __restrict__ out) {
  int row = blockIdx.x;
  const float* xr = x + (size_t)row * DM;
  int t = threadIdx.x;
  float v0 = xr[t], v1 = xr[t + 256];
  float s = v0 + v1;
  float sq = v0 * v0 + v1 * v1;
  for (int off = 32; off; off >>= 1) {
    s  += __shfl_xor(s, off);
    sq += __shfl_xor(sq, off);
  }
  __shared__ float ssum[4], ssq[4];
  int wave = t >> 6, lane = t & 63;
  if (lane == 0) { ssum[wave] = s; ssq[wave] = sq; }
  __syncthreads();
  if (t == 0) {
    float S = ssum[0] + ssum[1] + ssum[2] + ssum[3];
    float Q = ssq[0] + ssq[1] + ssq[2] + ssq[3];
    float mu = S * (1.0f / DM);
    float var = Q * (1.0f / DM) - mu * mu;
    ssum[0] = mu;
    ssq[0] = rsqrtf(var + 1e-5f);
  }
  __syncthreads();
  float mu = ssum[0], rstd = ssq[0];
  short* orow = out + (size_t)row * DM;
  orow[t]       = f2bf((v0 - mu) * rstd * gamma[t]       + beta[t]);
  orow[t + 256] = f2bf((v1 - mu) * rstd * gamma[t + 256] + beta[t + 256]);
}

// ---------------------------------------------------------------------------
// Weight convert+transpose fp32 [R][C] -> bf16 [C][R].
// ---------------------------------------------------------------------------
__global__ __launch_bounds__(256) void wconv_kernel(
    const float* Wq, const float* Wk, const float* Wv,
    const float* Wp, const float* W1, const float* W2,
    short* wqkv, short* wpt, short* w1t, short* w2t) {
  int z = blockIdx.z;
  const float* src; short* dst; int R, C;
  if (z < 24) {
    int m = z >> 3, hh = z & 7;
    const float* s0 = (m == 0) ? Wq : (m == 1) ? Wk : Wv;
    src = s0 + (size_t)hh * 512 * 64;
    dst = wqkv + ((size_t)(m * 512 + hh * 64)) * 512;
    R = 512; C = 64;
  } else if (z == 24) { src = Wp; dst = wpt; R = 512;  C = 512;  }
  else if (z == 25)   { src = W1; dst = w1t; R = 512;  C = 2048; }
  else                { src = W2; dst = w2t; R = 2048; C = 512;  }
  int tx = blockIdx.x, ty = blockIdx.y;
  if (tx >= C / 64 || ty >= R / 64) return;
  __shared__ float Ts[64][68];
  int t = threadIdx.x;
  int r = t >> 2, c0 = (t & 3) * 16;
  const float* sp = src + (size_t)(ty * 64 + r) * C + tx * 64 + c0;
#pragma unroll
  for (int i = 0; i < 16; i += 4) {
    float4 v = *(const float4*)(sp + i);
    Ts[c0 + i + 0][r] = v.x; Ts[c0 + i + 1][r] = v.y;
    Ts[c0 + i + 2][r] = v.z; Ts[c0 + i + 3][r] = v.w;
  }
  __syncthreads();
  short* dp = dst + (size_t)(tx * 64 + r) * R + ty * 64 + c0;
  short tmp[16];
#pragma unroll
  for (int i = 0; i < 16; ++i) tmp[i] = f2bf(Ts[r][c0 + i]);
  *(int4*)(dp)     = *(int4*)&tmp[0];
  *(int4*)(dp + 8) = *(int4*)&tmp[8];
}

// ---------------------------------------------------------------------------
// GEMM core v2 (R8): BK=32, double-buffered async staging, operand-swapped
// MFMA so each lane holds 4 consecutive N-columns -> coalesced epilogue.
// ---------------------------------------------------------------------------
template<int TM, int TN>
__device__ __forceinline__ void gemm_core(
    const short* __restrict__ A, const short* __restrict__ Bw,
    int m0, int n0, int K, short* smem, f32x4 (&acc)[TM / 32][TN / 32]) {
  constexpr int AF = TM / 32, BF = TN / 32;
  constexpr int AC = TM / 64, BC = TN / 64;   // staging calls (64 rows each)
  constexpr int BUFS = (TM + TN) * 32;        // shorts per buffer
  int t = threadIdx.x;
  int wave = t >> 6, lane = t & 63, quad = lane >> 4, l16 = lane & 15;
  int wr = wave >> 1, wc = wave & 1;

  size_t aoff[AC], boff[BC];
  int aldsoff[AC], bldsoff[BC];
#pragma unroll
  for (int c = 0; c < AC; ++c) {
    int p = c * 256 + t, row = p >> 2, lg = (p & 3) ^ ((row >> 1) & 3);
    aoff[c] = (size_t)(m0 + row) * K + lg * 8;
    aldsoff[c] = c * 2048 + wave * 512;
  }
#pragma unroll
  for (int c = 0; c < BC; ++c) {
    int p = c * 256 + t, row = p >> 2, lg = (p & 3) ^ ((row >> 1) & 3);
    boff[c] = (size_t)(n0 + row) * K + lg * 8;
    bldsoff[c] = TM * 32 + c * 2048 + wave * 512;
  }

  // stage tile 0 into buffer 0
#pragma unroll
  for (int c = 0; c < AC; ++c) gload16(A + aoff[c], smem + aldsoff[c]);
#pragma unroll
  for (int c = 0; c < BC; ++c) gload16(Bw + boff[c], smem + bldsoff[c]);

  int physo = (quad ^ ((l16 >> 1) & 3)) * 8;

  for (int k0 = 0; k0 < K; k0 += 32) {
    short* cbuf = smem + ((k0 >> 5) & 1) * BUFS;
    __syncthreads();  // drains tile-k0 loads; frees other buffer
    if (k0 + 32 < K) {
      short* nbuf = smem + (((k0 >> 5) & 1) ^ 1) * BUFS;
#pragma unroll
      for (int c = 0; c < AC; ++c) gload16(A + aoff[c] + k0 + 32, nbuf + aldsoff[c]);
#pragma unroll
      for (int c = 0; c < BC; ++c) gload16(Bw + boff[c] + k0 + 32, nbuf + bldsoff[c]);
    }
    bf16x8 af[AF], bfr[BF];
#pragma unroll
    for (int i = 0; i < AF; ++i)
      af[i] = *(const bf16x8*)&cbuf[(wr * (TM / 2) + i * 16 + l16) * 32 + physo];
#pragma unroll
    for (int j = 0; j < BF; ++j)
      bfr[j] = *(const bf16x8*)&cbuf[TM * 32 + (wc * (TN / 2) + j * 16 + l16) * 32 + physo];
#pragma unroll
    for (int i = 0; i < AF; ++i)
#pragma unroll
      for (int j = 0; j < BF; ++j)
        acc[i][j] = __builtin_amdgcn_mfma_f32_16x16x32_bf16(bfr[j], af[i], acc[i][j], 0, 0, 0);
  }
}

template<int TM, int TN>
__global__ __launch_bounds__(256) void mgemm_kernel(
    const short* __restrict__ A, const short* __restrict__ Bw,
    const float* __restrict__ bias, const float* __restrict__ res,
    void* __restrict__ C, int N, int K, int dorelu, int bf16out) {
  __shared__ __align__(16) short smem[(TM + TN) * 64];
  f32x4 acc[TM / 32][TN / 32];
  f32x4 zf = {0.f, 0.f, 0.f, 0.f};
#pragma unroll
  for (int i = 0; i < TM / 32; ++i)
#pragma unroll
    for (int j = 0; j < TN / 32; ++j) acc[i][j] = zf;
  int m0 = blockIdx.y * TM, n0 = blockIdx.x * TN;
  gemm_core<TM, TN>(A, Bw, m0, n0, K, smem, acc);

  int t = threadIdx.x;
  int wave = t >> 6, lane = t & 63, quad = lane >> 4, l16 = lane & 15;
  int wr = wave >> 1, wc = wave & 1;
#pragma unroll
  for (int i = 0; i < TM / 32; ++i) {
    int m = m0 + wr * (TM / 2) + i * 16 + l16;
#pragma unroll
    for (int j = 0; j < TN / 32; ++j) {
      int nb = n0 + wc * (TN / 2) + j * 16 + quad * 4;
      float4 bv = *(const float4*)&bias[nb];
      float v[4] = {acc[i][j][0] + bv.x, acc[i][j][1] + bv.y,
                    acc[i][j][2] + bv.z, acc[i][j][3] + bv.w};
      if (dorelu) {
#pragma unroll
        for (int r = 0; r < 4; ++r) v[r] = fmaxf(v[r], 0.0f);
      }
      size_t off = (size_t)m * N + nb;
      if (res) {
        float4 rv = *(const float4*)(res + off);
        v[0] += rv.x; v[1] += rv.y; v[2] += rv.z; v[3] += rv.w;
      }
      if (bf16out) {
        short tmp[4] = {f2bf(v[0]), f2bf(v[1]), f2bf(v[2]), f2bf(v[3])};
        *(int2*)((short*)C + off) = *(int2*)tmp;
      } else {
        float4 outv = {v[0], v[1], v[2], v[3]};
        *(float4*)((float*)C + off) = outv;
      }
    }
  }
}

// ---------------------------------------------------------------------------
// Fused QKV GEMM (q scaled by SCALE_Q; v written transposed per-head)
// ---------------------------------------------------------------------------
__global__ __launch_bounds__(256) void qkv_kernel(
    const short* __restrict__ A, const short* __restrict__ Bw,
    const float* __restrict__ bq, const float* __restrict__ bk,
    const float* __restrict__ bv,
    short* __restrict__ q, short* __restrict__ k, short* __restrict__ vt) {
  __shared__ __align__(16) short smem[17408];  // >= 16384 core; 128*136 Ts
  f32x4 acc[4][4];
  f32x4 zf = {0.f, 0.f, 0.f, 0.f};
#pragma unroll
  for (int i = 0; i < 4; ++i)
#pragma unroll
    for (int j = 0; j < 4; ++j) acc[i][j] = zf;
  int m0 = blockIdx.y * 128, n0 = blockIdx.x * 128;
  gemm_core<128, 128>(A, Bw, m0, n0, DM, smem, acc);

  int t = threadIdx.x;
  int wave = t >> 6, lane = t & 63, quad = lane >> 4, l16 = lane & 15;
  int wr = wave >> 1, wc = wave & 1;

  if (n0 < 1024) {
    short* out = (n0 < 512) ? q : k;
    const float* bias = (n0 < 512) ? bq + n0 : bk + (n0 - 512);
    float scale = (n0 < 512) ? SCALE_Q : 1.0f;
    int ncol0 = (n0 < 512) ? n0 : n0 - 512;
#pragma unroll
    for (int i = 0; i < 4; ++i) {
      int m = m0 + wr * 64 + i * 16 + l16;
#pragma unroll
      for (int j = 0; j < 4; ++j) {
        int nb = wc * 64 + j * 16 + quad * 4;
        float4 bvv = *(const float4*)&bias[nb];
        short tmp[4];
        tmp[0] = f2bf((acc[i][j][0] + bvv.x) * scale);
        tmp[1] = f2bf((acc[i][j][1] + bvv.y) * scale);
        tmp[2] = f2bf((acc[i][j][2] + bvv.z) * scale);
        tmp[3] = f2bf((acc[i][j][3] + bvv.w) * scale);
        *(int2*)(out + (size_t)m * DM + ncol0 + nb) = *(int2*)tmp;
      }
    }
  } else {
    const float* bias = bv + (n0 - 1024);
    __syncthreads();
    short* Ts = smem;  // [128][136]: Ts[n][m]
#pragma unroll
    for (int i = 0; i < 4; ++i) {
      int ml = wr * 64 + i * 16 + l16;
#pragma unroll
      for (int j = 0; j < 4; ++j) {
        int nb = wc * 64 + j * 16 + quad * 4;
        float4 bvv = *(const float4*)&bias[nb];
        Ts[(nb + 0) * 136 + ml] = f2bf(acc[i][j][0] + bvv.x);
        Ts[(nb + 1) * 136 + ml] = f2bf(acc[i][j][1] + bvv.y);
        Ts[(nb + 2) * 136 + ml] = f2bf(acc[i][j][2] + bvv.z);
        Ts[(nb + 3) * 136 + ml] = f2bf(acc[i][j][3] + bvv.w);
      }
    }
    __syncthreads();
    int nl = t >> 1, half = (t & 1) * 64;
    int gn = (n0 - 1024) + nl;
    int hh = gn >> 6, dk = gn & 63;
    int bidx = m0 >> 11, s0 = (m0 & 2047) + half;
    short* dst = vt + ((size_t)((bidx * NH + hh) * DK + dk)) * SEQ + s0;
    const short* srcT = &Ts[nl * 136 + half];
#pragma unroll
    for (int i2 = 0; i2 < 64; i2 += 8)
      *(int4*)(dst + i2) = *(const int4*)(srcT + i2);
  }
}

// ---------------------------------------------------------------------------
// Flash attention v6: BARRIER-FREE. K and V fragments loaded directly from
// global (per-(b,h) K+V = 512 KB -> L2; 32 KB tile -> L1 shared by 4 waves).
// LDS holds only the per-wave P round-trip. No-max softmax (exact: |s|<<88),
// S^T layout (lane-local l), exp2, q pre-scaled. 128-key tiles, K-frags
// shared across both 64-row q-frags. PV swapped -> b64 O-stores.
// grid (SEQ/128, NH, B); masked p = 0 (== exp(-1.25e8) in fp32).
// ---------------------------------------------------------------------------
__global__ __launch_bounds__(256) void fattn_kernel(
    const short* __restrict__ Q, const short* __restrict__ Kg,
    const short* __restrict__ Vt, short* __restrict__ O) {
  int qb = gridDim.x - 1 - blockIdx.x;  // heavy tiles dispatch first
  int h = blockIdx.y, b = blockIdx.z;
  int q0 = qb * 128;
  int t = threadIdx.x, wave = t >> 6, lane = t & 63, quad = lane >> 4, l16 = lane & 15;
  __shared__ __align__(16) short Ps[4][2][16 * 136]; // per-wave, per-frag P

  f32x4 zf = {0.f, 0.f, 0.f, 0.f};
  bf16x8 qf[2][2];
#pragma unroll
  for (int f = 0; f < 2; ++f) {
    const short* qp = Q + ((size_t)(b * SEQ + q0 + f * 64 + wave * 16 + l16)) * DM + h * DK;
    qf[f][0] = *(const bf16x8*)(qp + quad * 8);
    qf[f][1] = *(const bf16x8*)(qp + 32 + quad * 8);
  }

  f32x4 o_acc[2][4];   // [frag][dk-chunk]: regs = dk, lane = qrow
  float l_part[2] = {0.0f, 0.0f};
#pragma unroll
  for (int f = 0; f < 2; ++f)
#pragma unroll
    for (int j = 0; j < 4; ++j) o_acc[f][j] = zf;

  const short* kb = Kg + ((size_t)(b * SEQ)) * DM + h * DK;
  const short* vb = Vt + ((size_t)((b * NH + h) * DK)) * SEQ;
  int qrow0 = q0 + wave * 16 + l16;
  int qrow1 = qrow0 + 64;

  for (int kt = 0; kt <= qb; ++kt) {
    bool diag = (kt == qb);
    int key0 = kt * 128;

    // ---- S^T + softmax for both frags (K-frag loaded once) ----
#pragma unroll
    for (int nt = 0; nt < 8; ++nt) {
      const short* kp = kb + (size_t)(key0 + nt * 16 + l16) * DM;
      bf16x8 ka0 = *(const bf16x8*)(kp + quad * 8);
      bf16x8 ka1 = *(const bf16x8*)(kp + 32 + quad * 8);
      f32x4 s0 = __builtin_amdgcn_mfma_f32_16x16x32_bf16(ka0, qf[0][0], zf, 0, 0, 0);
      s0 = __builtin_amdgcn_mfma_f32_16x16x32_bf16(ka1, qf[0][1], s0, 0, 0, 0);
      f32x4 s1 = __builtin_amdgcn_mfma_f32_16x16x32_bf16(ka0, qf[1][0], zf, 0, 0, 0);
      s1 = __builtin_amdgcn_mfma_f32_16x16x32_bf16(ka1, qf[1][1], s1, 0, 0, 0);
      int keyb = key0 + nt * 16 + quad * 4;
      {
        short tmp[4];
#pragma unroll
        for (int r = 0; r < 4; ++r) {
          float p = (diag && (keyb + r > qrow0)) ? 0.0f : exp2f(s0[r]);
          l_part[0] += p;
          tmp[r] = f2bf(p);
        }
        *(int2*)&Ps[wave][0][l16 * 136 + nt * 16 + quad * 4] = *(int2*)tmp;
      }
      {
        short tmp[4];
#pragma unroll
        for (int r = 0; r < 4; ++r) {
          float p = (diag && (keyb + r > qrow1)) ? 0.0f : exp2f(s1[r]);
          l_part[1] += p;
          tmp[r] = f2bf(p);
        }
        *(int2*)&Ps[wave][1][l16 * 136 + nt * 16 + quad * 4] = *(int2*)tmp;
      }
    }

    // ---- PV per frag (V-frags from global; f=1 reload hits L1) ----
#pragma unroll
    for (int f = 0; f < 2; ++f) {
      bf16x8 apf[4];
#pragma unroll
      for (int kc = 0; kc < 4; ++kc)
        apf[kc] = *(const bf16x8*)&Ps[wave][f][l16 * 136 + kc * 32 + quad * 8];
#pragma unroll
      for (int nt2 = 0; nt2 < 4; ++nt2) {
        const short* vp = vb + (size_t)(nt2 * 16 + l16) * SEQ + key0;
#pragma unroll
        for (int kc = 0; kc < 4; ++kc) {
          bf16x8 vf = *(const bf16x8*)(vp + kc * 32 + quad * 8);
          o_acc[f][nt2] = __builtin_amdgcn_mfma_f32_16x16x32_bf16(vf, apf[kc], o_acc[f][nt2], 0, 0, 0);
        }
      }
    }
  }

#pragma unroll
  for (int f = 0; f < 2; ++f) {
    float lf = l_part[f];
    lf += __shfl_xor(lf, 16);
    lf += __shfl_xor(lf, 32);   // lanes sharing l16 hold full l for qrow
    float inv = 1.0f / lf;      // this lane's qrow = rb + l16
    int rb = q0 + f * 64 + wave * 16;
    short* orow = O + ((size_t)(b * SEQ) + rb + l16) * DM + h * DK;
#pragma unroll
    for (int nt2 = 0; nt2 < 4; ++nt2) {
      short tmp[4];
#pragma unroll
      for (int r = 0; r < 4; ++r) tmp[r] = f2bf(o_acc[f][nt2][r] * inv);
      *(int2*)(orow + nt2 * 16 + quad * 4) = *(int2*)tmp;
    }
  }
}

// ---------------------------------------------------------------------------
extern "C" void kernel_launch(void* const* d_in, const int* in_sizes, int n_in,
                              void* d_out, int out_size, void* d_ws, size_t ws_size,
                              hipStream_t stream) {
  const float* x   = (const float*)d_in[0];
  const float* Wq  = (const float*)d_in[1];
  const float* bq  = (const float*)d_in[2];
  const float* Wk  = (const float*)d_in[3];
  const float* bk  = (const float*)d_in[4];
  const float* Wv  = (const float*)d_in[5];
  const float* bv  = (const float*)d_in[6];
  const float* Wp  = (const float*)d_in[7];
  const float* bp  = (const float*)d_in[8];
  const float* W1  = (const float*)d_in[9];
  const float* b1  = (const float*)d_in[10];
  const float* W2  = (const float*)d_in[11];
  const float* b2  = (const float*)d_in[12];
  const float* g1  = (const float*)d_in[13];
  const float* be1 = (const float*)d_in[14];
  const float* g2  = (const float*)d_in[15];
  const float* be2 = (const float*)d_in[16];
  float* out = (float*)d_out;

  char* wsb = (char*)d_ws;
  const size_t SB = (size_t)BT * DM * 2;  // 8 MB
  short* h    = (short*)(wsb);
  short* q    = (short*)(wsb + SB);
  short* k    = (short*)(wsb + 2 * SB);
  short* vt   = (short*)(wsb + 3 * SB);
  short* o    = (short*)(wsb + 4 * SB);
  float* x2   = (float*)(wsb + 5 * SB);                       // 16 MB
  short* h2   = (short*)(wsb + 5 * SB + (size_t)BT * DM * 4);
  short* ff   = (short*)(wsb + 6 * SB + (size_t)BT * DM * 4); // 32 MB
  short* wqkv = (short*)(wsb + 6 * SB + (size_t)BT * DM * 4 + (size_t)BT * FF * 2);
  short* wpt  = wqkv + 1536 * 512;
  short* w1t  = wpt + 512 * 512;
  short* w2t  = w1t + 2048 * 512;

  dim3 blk(256);

  wconv_kernel<<<dim3(32, 32, 27), blk, 0, stream>>>(Wq, Wk, Wv, Wp, W1, W2,
                                                     wqkv, wpt, w1t, w2t);
  ln_kernel<<<BT, blk, 0, stream>>>(x, g1, be1, h);

  qkv_kernel<<<dim3(12, 64), blk, 0, stream>>>(h, wqkv, bq, bk, bv, q, k, vt);

  fattn_kernel<<<dim3(SEQ / 128, NH, BATCH), blk, 0, stream>>>(q, k, vt, o);

  mgemm_kernel<64, 64><<<dim3(8, 128), blk, 0, stream>>>(o, wpt, bp, x, x2, DM, DM, 0, 0);
  ln_kernel<<<BT, blk, 0, stream>>>(x2, g2, be2, h2);
  mgemm_kernel<128, 128><<<dim3(16, 64), blk, 0, stream>>>(h2, w1t, b1, nullptr, ff, FF, DM, 1, 1);
  mgemm_kernel<64, 64><<<dim3(8, 128), blk, 0, stream>>>(ff, w2t, b2, x2, out, DM, FF, 0, 0);
}

// Round 10
// 315.267 us; speedup vs baseline: 1.2394x; 1.2394x over previous
//
#include <hip/hip_runtime.h>
#include <hip/hip_bf16.h>
#include <math.h>

#define BATCH 4
#define SEQ   2048
#define DM    512
#define NH    8
#define DK    64
#define FF    2048
#define BT    (BATCH * SEQ)   // 8192

// q pre-scale: 0.125 * log2(e)  -> softmax uses exp2 directly
#define SCALE_Q 0.18033688011112042f

typedef short bf16x8 __attribute__((ext_vector_type(8)));
typedef float f32x4  __attribute__((ext_vector_type(4)));

static __device__ inline short f2bf(float f) {
  union { float f; unsigned u; } v; v.f = f;
  unsigned r = (v.u + 0x7fffu + ((v.u >> 16) & 1u)) >> 16;
  return (short)r;
}

// async 16B global->LDS (gfx950). LDS dest = wave-uniform base + lane*16.
static __device__ __forceinline__ void gload16(const short* g, short* l) {
  __builtin_amdgcn_global_load_lds(
      (const __attribute__((address_space(1))) void*)g,
      (__attribute__((address_space(3))) void*)l, 16, 0, 0);
}

// ---------------------------------------------------------------------------
// LayerNorm: one block per row of 512, fp32 in -> bf16 out
// ---------------------------------------------------------------------------
__global__ __launch_bounds__(256) void ln_kernel(
    const float* __restrict__ x, const float* __restrict__ gamma,
    const float* __restrict__ beta, short* __restrict__ out) {
  int row = blockIdx.x;
  const float* xr = x + (size_t)row * DM;
  int t = threadIdx.x;
  float v0 = xr[t], v1 = xr[t + 256];
  float s = v0 + v1;
  float sq = v0 * v0 + v1 * v1;
  for (int off = 32; off; off >>= 1) {
    s  += __shfl_xor(s, off);
    sq += __shfl_xor(sq, off);
  }
  __shared__ float ssum[4], ssq[4];
  int wave = t >> 6, lane = t & 63;
  if (lane == 0) { ssum[wave] = s; ssq[wave] = sq; }
  __syncthreads();
  if (t == 0) {
    float S = ssum[0] + ssum[1] + ssum[2] + ssum[3];
    float Q = ssq[0] + ssq[1] + ssq[2] + ssq[3];
    float mu = S * (1.0f / DM);
    float var = Q * (1.0f / DM) - mu * mu;
    ssum[0] = mu;
    ssq[0] = rsqrtf(var + 1e-5f);
  }
  __syncthreads();
  float mu = ssum[0], rstd = ssq[0];
  short* orow = out + (size_t)row * DM;
  orow[t]       = f2bf((v0 - mu) * rstd * gamma[t]       + beta[t]);
  orow[t + 256] = f2bf((v1 - mu) * rstd * gamma[t + 256] + beta[t + 256]);
}

// ---------------------------------------------------------------------------
// Weight convert+transpose fp32 [R][C] -> bf16 [C][R].
// ---------------------------------------------------------------------------
__global__ __launch_bounds__(256) void wconv_kernel(
    const float* Wq, const float* Wk, const float* Wv,
    const float* Wp, const float* W1, const float* W2,
    short* wqkv, short* wpt, short* w1t, short* w2t) {
  int z = blockIdx.z;
  const float* src; short* dst; int R, C;
  if (z < 24) {
    int m = z >> 3, hh = z & 7;
    const float* s0 = (m == 0) ? Wq : (m == 1) ? Wk : Wv;
    src = s0 + (size_t)hh * 512 * 64;
    dst = wqkv + ((size_t)(m * 512 + hh * 64)) * 512;
    R = 512; C = 64;
  } else if (z == 24) { src = Wp; dst = wpt; R = 512;  C = 512;  }
  else if (z == 25)   { src = W1; dst = w1t; R = 512;  C = 2048; }
  else                { src = W2; dst = w2t; R = 2048; C = 512;  }
  int tx = blockIdx.x, ty = blockIdx.y;
  if (tx >= C / 64 || ty >= R / 64) return;
  __shared__ float Ts[64][68];
  int t = threadIdx.x;
  int r = t >> 2, c0 = (t & 3) * 16;
  const float* sp = src + (size_t)(ty * 64 + r) * C + tx * 64 + c0;
#pragma unroll
  for (int i = 0; i < 16; i += 4) {
    float4 v = *(const float4*)(sp + i);
    Ts[c0 + i + 0][r] = v.x; Ts[c0 + i + 1][r] = v.y;
    Ts[c0 + i + 2][r] = v.z; Ts[c0 + i + 3][r] = v.w;
  }
  __syncthreads();
  short* dp = dst + (size_t)(tx * 64 + r) * R + ty * 64 + c0;
  short tmp[16];
#pragma unroll
  for (int i = 0; i < 16; ++i) tmp[i] = f2bf(Ts[r][c0 + i]);
  *(int4*)(dp)     = *(int4*)&tmp[0];
  *(int4*)(dp + 8) = *(int4*)&tmp[8];
}

// ---------------------------------------------------------------------------
// GEMM core (R8): BK=32, double-buffered async staging, operand-swapped
// MFMA so each lane holds 4 consecutive N-columns -> coalesced epilogue.
// ---------------------------------------------------------------------------
template<int TM, int TN>
__device__ __forceinline__ void gemm_core(
    const short* __restrict__ A, const short* __restrict__ Bw,
    int m0, int n0, int K, short* smem, f32x4 (&acc)[TM / 32][TN / 32]) {
  constexpr int AF = TM / 32, BF = TN / 32;
  constexpr int AC = TM / 64, BC = TN / 64;   // staging calls (64 rows each)
  constexpr int BUFS = (TM + TN) * 32;        // shorts per buffer
  int t = threadIdx.x;
  int wave = t >> 6, lane = t & 63, quad = lane >> 4, l16 = lane & 15;
  int wr = wave >> 1, wc = wave & 1;

  size_t aoff[AC], boff[BC];
  int aldsoff[AC], bldsoff[BC];
#pragma unroll
  for (int c = 0; c < AC; ++c) {
    int p = c * 256 + t, row = p >> 2, lg = (p & 3) ^ ((row >> 1) & 3);
    aoff[c] = (size_t)(m0 + row) * K + lg * 8;
    aldsoff[c] = c * 2048 + wave * 512;
  }
#pragma unroll
  for (int c = 0; c < BC; ++c) {
    int p = c * 256 + t, row = p >> 2, lg = (p & 3) ^ ((row >> 1) & 3);
    boff[c] = (size_t)(n0 + row) * K + lg * 8;
    bldsoff[c] = TM * 32 + c * 2048 + wave * 512;
  }

  // stage tile 0 into buffer 0
#pragma unroll
  for (int c = 0; c < AC; ++c) gload16(A + aoff[c], smem + aldsoff[c]);
#pragma unroll
  for (int c = 0; c < BC; ++c) gload16(Bw + boff[c], smem + bldsoff[c]);

  int physo = (quad ^ ((l16 >> 1) & 3)) * 8;

  for (int k0 = 0; k0 < K; k0 += 32) {
    short* cbuf = smem + ((k0 >> 5) & 1) * BUFS;
    __syncthreads();  // drains tile-k0 loads; frees other buffer
    if (k0 + 32 < K) {
      short* nbuf = smem + (((k0 >> 5) & 1) ^ 1) * BUFS;
#pragma unroll
      for (int c = 0; c < AC; ++c) gload16(A + aoff[c] + k0 + 32, nbuf + aldsoff[c]);
#pragma unroll
      for (int c = 0; c < BC; ++c) gload16(Bw + boff[c] + k0 + 32, nbuf + bldsoff[c]);
    }
    bf16x8 af[AF], bfr[BF];
#pragma unroll
    for (int i = 0; i < AF; ++i)
      af[i] = *(const bf16x8*)&cbuf[(wr * (TM / 2) + i * 16 + l16) * 32 + physo];
#pragma unroll
    for (int j = 0; j < BF; ++j)
      bfr[j] = *(const bf16x8*)&cbuf[TM * 32 + (wc * (TN / 2) + j * 16 + l16) * 32 + physo];
#pragma unroll
    for (int i = 0; i < AF; ++i)
#pragma unroll
      for (int j = 0; j < BF; ++j)
        acc[i][j] = __builtin_amdgcn_mfma_f32_16x16x32_bf16(bfr[j], af[i], acc[i][j], 0, 0, 0);
  }
}

template<int TM, int TN>
__global__ __launch_bounds__(256) void mgemm_kernel(
    const short* __restrict__ A, const short* __restrict__ Bw,
    const float* __restrict__ bias, const float* __restrict__ res,
    void* __restrict__ C, int N, int K, int dorelu, int bf16out) {
  __shared__ __align__(16) short smem[(TM + TN) * 64];
  f32x4 acc[TM / 32][TN / 32];
  f32x4 zf = {0.f, 0.f, 0.f, 0.f};
#pragma unroll
  for (int i = 0; i < TM / 32; ++i)
#pragma unroll
    for (int j = 0; j < TN / 32; ++j) acc[i][j] = zf;
  int m0 = blockIdx.y * TM, n0 = blockIdx.x * TN;
  gemm_core<TM, TN>(A, Bw, m0, n0, K, smem, acc);

  int t = threadIdx.x;
  int wave = t >> 6, lane = t & 63, quad = lane >> 4, l16 = lane & 15;
  int wr = wave >> 1, wc = wave & 1;
#pragma unroll
  for (int i = 0; i < TM / 32; ++i) {
    int m = m0 + wr * (TM / 2) + i * 16 + l16;
#pragma unroll
    for (int j = 0; j < TN / 32; ++j) {
      int nb = n0 + wc * (TN / 2) + j * 16 + quad * 4;
      float4 bv = *(const float4*)&bias[nb];
      float v[4] = {acc[i][j][0] + bv.x, acc[i][j][1] + bv.y,
                    acc[i][j][2] + bv.z, acc[i][j][3] + bv.w};
      if (dorelu) {
#pragma unroll
        for (int r = 0; r < 4; ++r) v[r] = fmaxf(v[r], 0.0f);
      }
      size_t off = (size_t)m * N + nb;
      if (res) {
        float4 rv = *(const float4*)(res + off);
        v[0] += rv.x; v[1] += rv.y; v[2] += rv.z; v[3] += rv.w;
      }
      if (bf16out) {
        short tmp[4] = {f2bf(v[0]), f2bf(v[1]), f2bf(v[2]), f2bf(v[3])};
        *(int2*)((short*)C + off) = *(int2*)tmp;
      } else {
        float4 outv = {v[0], v[1], v[2], v[3]};
        *(float4*)((float*)C + off) = outv;
      }
    }
  }
}

// ---------------------------------------------------------------------------
// Fused QKV GEMM (q scaled by SCALE_Q; v written transposed per-head)
// ---------------------------------------------------------------------------
__global__ __launch_bounds__(256) void qkv_kernel(
    const short* __restrict__ A, const short* __restrict__ Bw,
    const float* __restrict__ bq, const float* __restrict__ bk,
    const float* __restrict__ bv,
    short* __restrict__ q, short* __restrict__ k, short* __restrict__ vt) {
  __shared__ __align__(16) short smem[17408];  // >= 16384 core; 128*136 Ts
  f32x4 acc[4][4];
  f32x4 zf = {0.f, 0.f, 0.f, 0.f};
#pragma unroll
  for (int i = 0; i < 4; ++i)
#pragma unroll
    for (int j = 0; j < 4; ++j) acc[i][j] = zf;
  int m0 = blockIdx.y * 128, n0 = blockIdx.x * 128;
  gemm_core<128, 128>(A, Bw, m0, n0, DM, smem, acc);

  int t = threadIdx.x;
  int wave = t >> 6, lane = t & 63, quad = lane >> 4, l16 = lane & 15;
  int wr = wave >> 1, wc = wave & 1;

  if (n0 < 1024) {
    short* out = (n0 < 512) ? q : k;
    const float* bias = (n0 < 512) ? bq + n0 : bk + (n0 - 512);
    float scale = (n0 < 512) ? SCALE_Q : 1.0f;
    int ncol0 = (n0 < 512) ? n0 : n0 - 512;
#pragma unroll
    for (int i = 0; i < 4; ++i) {
      int m = m0 + wr * 64 + i * 16 + l16;
#pragma unroll
      for (int j = 0; j < 4; ++j) {
        int nb = wc * 64 + j * 16 + quad * 4;
        float4 bvv = *(const float4*)&bias[nb];
        short tmp[4];
        tmp[0] = f2bf((acc[i][j][0] + bvv.x) * scale);
        tmp[1] = f2bf((acc[i][j][1] + bvv.y) * scale);
        tmp[2] = f2bf((acc[i][j][2] + bvv.z) * scale);
        tmp[3] = f2bf((acc[i][j][3] + bvv.w) * scale);
        *(int2*)(out + (size_t)m * DM + ncol0 + nb) = *(int2*)tmp;
      }
    }
  } else {
    const float* bias = bv + (n0 - 1024);
    __syncthreads();
    short* Ts = smem;  // [128][136]: Ts[n][m]
#pragma unroll
    for (int i = 0; i < 4; ++i) {
      int ml = wr * 64 + i * 16 + l16;
#pragma unroll
      for (int j = 0; j < 4; ++j) {
        int nb = wc * 64 + j * 16 + quad * 4;
        float4 bvv = *(const float4*)&bias[nb];
        Ts[(nb + 0) * 136 + ml] = f2bf(acc[i][j][0] + bvv.x);
        Ts[(nb + 1) * 136 + ml] = f2bf(acc[i][j][1] + bvv.y);
        Ts[(nb + 2) * 136 + ml] = f2bf(acc[i][j][2] + bvv.z);
        Ts[(nb + 3) * 136 + ml] = f2bf(acc[i][j][3] + bvv.w);
      }
    }
    __syncthreads();
    int nl = t >> 1, half = (t & 1) * 64;
    int gn = (n0 - 1024) + nl;
    int hh = gn >> 6, dk = gn & 63;
    int bidx = m0 >> 11, s0 = (m0 & 2047) + half;
    short* dst = vt + ((size_t)((bidx * NH + hh) * DK + dk)) * SEQ + s0;
    const short* srcT = &Ts[nl * 136 + half];
#pragma unroll
    for (int i2 = 0; i2 < 64; i2 += 8)
      *(int4*)(dst + i2) = *(const int4*)(srcT + i2);
  }
}

// ---------------------------------------------------------------------------
// Flash attention v7: SMALL quanta for occupancy. 64 q-rows x 64-key tiles,
// grid (32, NH, B) = 1024 blocks, LDS 25.6 KB -> 4-6 blocks/CU.
// LDS-staged swizzled K/V (async), no-max softmax (exact: |s| << 88), exp2,
// S^T layout (lane-local l), v_perm truncation pack for P (bias cancels in
// softmax ratio), PV operand-swapped -> b64 O-stores. Masked p = 0.
// ---------------------------------------------------------------------------
__global__ __launch_bounds__(256) void fattn_kernel(
    const short* __restrict__ Q, const short* __restrict__ Kg,
    const short* __restrict__ Vt, short* __restrict__ O) {
  int qt = 31 - blockIdx.x;  // heavy tiles dispatch first
  int h = blockIdx.y, b = blockIdx.z;
  int q0 = qt * 64;
  int t = threadIdx.x, wave = t >> 6, lane = t & 63, quad = lane >> 4, l16 = lane & 15;
  __shared__ __align__(16) short Ks[64 * 64];   // [key][dk], 8-chunk swizzle
  __shared__ __align__(16) short Vs[64 * 64];   // [dk][key], 8-chunk swizzle
  __shared__ __align__(16) short Ps[4][16 * 72];// per-wave P [qrow][key]

  f32x4 zf = {0.f, 0.f, 0.f, 0.f};
  const short* qp = Q + ((size_t)(b * SEQ + q0 + wave * 16 + l16)) * DM + h * DK;
  bf16x8 qf0 = *(const bf16x8*)(qp + quad * 8);
  bf16x8 qf1 = *(const bf16x8*)(qp + 32 + quad * 8);

  f32x4 o_acc[4];   // regs = dk (quad*4+r within nt2*16), lane col = qrow
  float l_part = 0.0f;
#pragma unroll
  for (int j = 0; j < 4; ++j) o_acc[j] = zf;

  const short* kb = Kg + ((size_t)(b * SEQ)) * DM + h * DK;
  const short* vb = Vt + ((size_t)((b * NH + h) * DK)) * SEQ;
  size_t koff[2], voff[2];
  short *klds[2], *vlds[2];
#pragma unroll
  for (int c = 0; c < 2; ++c) {
    int p = c * 256 + t;
    int row = p >> 3, lg = (p & 7) ^ (row & 7);
    koff[c] = (size_t)row * DM + lg * 8;
    klds[c] = Ks + c * 2048 + wave * 512;
    voff[c] = (size_t)row * SEQ + lg * 8;
    vlds[c] = Vs + c * 2048 + wave * 512;
  }
  int qrow = q0 + wave * 16 + l16;

  for (int kt = 0; kt <= qt; ++kt) {
    __syncthreads();
    gload16(kb + koff[0] + (size_t)kt * 64 * DM, klds[0]);
    gload16(kb + koff[1] + (size_t)kt * 64 * DM, klds[1]);
    gload16(vb + voff[0] + kt * 64, vlds[0]);
    gload16(vb + voff[1] + kt * 64, vlds[1]);
    __syncthreads();
    bool diag = (kt == qt);

    // S^T: key = nt*16+quad*4+r (rows), qrow = q0+wave*16+l16 (cols)
#pragma unroll
    for (int nt = 0; nt < 4; ++nt) {
      int krow = nt * 16 + l16, sw = krow & 7;
      bf16x8 ka0 = *(const bf16x8*)&Ks[krow * 64 + (quad ^ sw) * 8];
      bf16x8 ka1 = *(const bf16x8*)&Ks[krow * 64 + ((4 + quad) ^ sw) * 8];
      f32x4 s = __builtin_amdgcn_mfma_f32_16x16x32_bf16(ka0, qf0, zf, 0, 0, 0);
      s = __builtin_amdgcn_mfma_f32_16x16x32_bf16(ka1, qf1, s, 0, 0, 0);
      int keyb = kt * 64 + nt * 16 + quad * 4;
      float pr[4];
#pragma unroll
      for (int r = 0; r < 4; ++r) {
        float e = exp2f(s[r]);
        pr[r] = (diag && (keyb + r > qrow)) ? 0.0f : e;
        l_part += pr[r];
      }
      // truncation-pack two f32 -> packed bf16x2 in 1 v_perm each
      unsigned pk0 = __builtin_amdgcn_perm(
          __float_as_uint(pr[1]), __float_as_uint(pr[0]), 0x07060302u);
      unsigned pk1 = __builtin_amdgcn_perm(
          __float_as_uint(pr[3]), __float_as_uint(pr[2]), 0x07060302u);
      int2 w = {(int)pk0, (int)pk1};
      *(int2*)&Ps[wave][l16 * 72 + nt * 16 + quad * 4] = w;
    }

    // PV: O += V^T P  (A = V^T rows = dk, B = P cols = qrow)
    bf16x8 apf0 = *(const bf16x8*)&Ps[wave][l16 * 72 + quad * 8];
    bf16x8 apf1 = *(const bf16x8*)&Ps[wave][l16 * 72 + 32 + quad * 8];
#pragma unroll
    for (int nt2 = 0; nt2 < 4; ++nt2) {
      int vrow = nt2 * 16 + l16, sw = vrow & 7;
      bf16x8 vf0 = *(const bf16x8*)&Vs[vrow * 64 + (quad ^ sw) * 8];
      bf16x8 vf1 = *(const bf16x8*)&Vs[vrow * 64 + ((4 + quad) ^ sw) * 8];
      o_acc[nt2] = __builtin_amdgcn_mfma_f32_16x16x32_bf16(vf0, apf0, o_acc[nt2], 0, 0, 0);
      o_acc[nt2] = __builtin_amdgcn_mfma_f32_16x16x32_bf16(vf1, apf1, o_acc[nt2], 0, 0, 0);
    }
  }

  float lf = l_part;
  lf += __shfl_xor(lf, 16);
  lf += __shfl_xor(lf, 32);   // all lanes sharing l16 hold full row sum
  float inv = 1.0f / lf;      // this lane's qrow
  short* orow = O + ((size_t)(b * SEQ) + qrow) * DM + h * DK;
#pragma unroll
  for (int nt2 = 0; nt2 < 4; ++nt2) {
    short tmp[4];
#pragma unroll
    for (int r = 0; r < 4; ++r) tmp[r] = f2bf(o_acc[nt2][r] * inv);
    *(int2*)(orow + nt2 * 16 + quad * 4) = *(int2*)tmp;
  }
}

// ---------------------------------------------------------------------------
extern "C" void kernel_launch(void* const* d_in, const int* in_sizes, int n_in,
                              void* d_out, int out_size, void* d_ws, size_t ws_size,
                              hipStream_t stream) {
  const float* x   = (const float*)d_in[0];
  const float* Wq  = (const float*)d_in[1];
  const float* bq  = (const float*)d_in[2];
  const float* Wk  = (const float*)d_in[3];
  const float* bk  = (const float*)d_in[4];
  const float* Wv  = (const float*)d_in[5];
  const float* bv  = (const float*)d_in[6];
  const float* Wp  = (const float*)d_in[7];
  const float* bp  = (const float*)d_in[8];
  const float* W1  = (const float*)d_in[9];
  const float* b1  = (const float*)d_in[10];
  const float* W2  = (const float*)d_in[11];
  const float* b2  = (const float*)d_in[12];
  const float* g1  = (const float*)d_in[13];
  const float* be1 = (const float*)d_in[14];
  const float* g2  = (const float*)d_in[15];
  const float* be2 = (const float*)d_in[16];
  float* out = (float*)d_out;

  char* wsb = (char*)d_ws;
  const size_t SB = (size_t)BT * DM * 2;  // 8 MB
  short* h    = (short*)(wsb);
  short* q    = (short*)(wsb + SB);
  short* k    = (short*)(wsb + 2 * SB);
  short* vt   = (short*)(wsb + 3 * SB);
  short* o    = (short*)(wsb + 4 * SB);
  float* x2   = (float*)(wsb + 5 * SB);                       // 16 MB
  short* h2   = (short*)(wsb + 5 * SB + (size_t)BT * DM * 4);
  short* ff   = (short*)(wsb + 6 * SB + (size_t)BT * DM * 4); // 32 MB
  short* wqkv = (short*)(wsb + 6 * SB + (size_t)BT * DM * 4 + (size_t)BT * FF * 2);
  short* wpt  = wqkv + 1536 * 512;
  short* w1t  = wpt + 512 * 512;
  short* w2t  = w1t + 2048 * 512;

  dim3 blk(256);

  wconv_kernel<<<dim3(32, 32, 27), blk, 0, stream>>>(Wq, Wk, Wv, Wp, W1, W2,
                                                     wqkv, wpt, w1t, w2t);
  ln_kernel<<<BT, blk, 0, stream>>>(x, g1, be1, h);

  qkv_kernel<<<dim3(12, 64), blk, 0, stream>>>(h, wqkv, bq, bk, bv, q, k, vt);

  fattn_kernel<<<dim3(32, NH, BATCH), blk, 0, stream>>>(q, k, vt, o);

  mgemm_kernel<64, 64><<<dim3(8, 128), blk, 0, stream>>>(o, wpt, bp, x, x2, DM, DM, 0, 0);
  ln_kernel<<<BT, blk, 0, stream>>>(x2, g2, be2, h2);
  mgemm_kernel<128, 128><<<dim3(16, 64), blk, 0, stream>>>(h2, w1t, b1, nullptr, ff, FF, DM, 1, 1);
  mgemm_kernel<64, 64><<<dim3(8, 128), blk, 0, stream>>>(ff, w2t, b2, x2, out, DM, FF, 0, 0);
}